// Round 7
// baseline (2205.778 us; speedup 1.0000x reference)
//
#include <hip/hip_runtime.h>

#define TWO_PI 6.2831853071795864769f
#define SP3 327680      // 128*128*20
#define YT 2560         // 128*20

static __device__ __forceinline__ float gelu_f(float u){
  return 0.5f*u*(1.0f+erff(u*0.7071067811865475f));
}

// ---------------- fc0: x(B,X,Y,T,5) @ (5,20) + b -> h(B,32stride,X,Y,T), 20 ch ----
__global__ void k_fc0(const float* __restrict__ x, const float* __restrict__ w,
                      const float* __restrict__ bias, float* __restrict__ h){
  __shared__ float wl[100], bl[20];
  int tid=threadIdx.x;
  if(tid<100) wl[tid]=w[tid];
  if(tid<20) bl[tid]=bias[tid];
  __syncthreads();
  int p=blockIdx.x*256+tid;          // 0..1310719
  int b=p/SP3, sp=p-b*SP3;
  const float* xp=x+(long)p*5;
  float xi[5];
  #pragma unroll
  for(int i=0;i<5;i++) xi[i]=xp[i];
  float* hb=h+(long)(b*32)*SP3+sp;
  #pragma unroll
  for(int c=0;c<20;c++){
    float a=bl[c];
    #pragma unroll
    for(int i=0;i<5;i++) a+=xi[i]*wl[i*20+c];
    hb[(long)c*SP3]=a;
  }
}

// ------------- forward T+Y DFT over 8-x slabs. Direct global float4 row reads.
// block: 512 threads; grid: nb*Ci*16. out: Fty[(b*32+c)*128+x][slot2*8+kz] float2.
template<int M2>
__global__ __launch_bounds__(512,3) void k_fwd_ty8(const float* __restrict__ h,
                                                   float* __restrict__ Fty, int Ci){
  constexpr int J=2*M2*8;
  constexpr int ITEMS=2*M2*32;          // (slot, xl(4), kz(8)) items per half
  __shared__ float2 Gc[128*33];         // 33792 B, [y][col=xl*8+kz], pad 33
  __shared__ __align__(16) float2 tw20[160];
  __shared__ float2 tw128[128];
  int tid=threadIdx.x;
  int bid=blockIdx.x;
  int xg=bid&15, bc=bid>>4; int c=bc%Ci, b=bc/Ci;
  int x0=xg*8;
  for(int i=tid;i<160;i+=512){ int t=i>>3,kz=i&7; float s,cc;
    sincosf(TWO_PI*((kz*t)%20)/20.0f,&s,&cc); tw20[i]=make_float2(cc,s); }
  if(tid<128){ float s,cc; sincosf(TWO_PI*tid/128.0f,&s,&cc); tw128[tid]=make_float2(cc,s); }
  __syncthreads();
  const float* hb=h+(long)(b*32+c)*SP3+x0*YT;
  float2* outp=(float2*)Fty+((long)(b*32+c)*128+x0)*J;
  const float4* twp=(const float4*)tw20;   // [t*4+q] -> (c,s) for kz=2q,2q+1

  for(int half=0;half<2;half++){
    if(half) __syncthreads();             // protect Gc from prev half readers
    // ---- T-DFT: one row per thread, direct global float4 reads
    {
      int y=tid&127, xl=tid>>7;
      const float* rp=hb+(half*4+xl)*YT+y*20;
      float4 r0=*(const float4*)(rp);
      float4 r1=*(const float4*)(rp+4);
      float4 r2=*(const float4*)(rp+8);
      float4 r3=*(const float4*)(rp+12);
      float4 r4=*(const float4*)(rp+16);
      float row[20]={r0.x,r0.y,r0.z,r0.w, r1.x,r1.y,r1.z,r1.w, r2.x,r2.y,r2.z,r2.w,
                     r3.x,r3.y,r3.z,r3.w, r4.x,r4.y,r4.z,r4.w};
      float re[8],im[8];
      #pragma unroll
      for(int kz=0;kz<8;kz++){re[kz]=0.f;im[kz]=0.f;}
      #pragma unroll
      for(int t=0;t<20;t++){
        float v=row[t];
        #pragma unroll
        for(int q=0;q<4;q++){
          float4 w=twp[t*4+q];
          re[2*q]  +=v*w.x; im[2*q]  -=v*w.y;
          re[2*q+1]+=v*w.z; im[2*q+1]-=v*w.w;
        }
      }
      #pragma unroll
      for(int kz=0;kz<8;kz++) Gc[y*33+xl*8+kz]=make_float2(re[kz],im[kz]);
    }
    __syncthreads();
    // ---- Y-DFT: item = (slot s, col=(xl,kz)), incremental twiddle
    for(int idx=tid;idx<ITEMS;idx+=512){
      int col=idx&31, s=idx>>5;
      int km=(s<M2)?s:(s-2*M2);
      float accr=0.f, acci=0.f; int jj=0;
      for(int y=0;y<128;y++){
        float2 w=tw128[jj];
        float2 d=Gc[y*33+col];
        accr+=d.x*w.x+d.y*w.y;
        acci+=d.y*w.x-d.x*w.y;
        jj=(jj+km)&127;
      }
      outp[(long)(half*4+(col>>3))*J+s*8+(col&7)]=make_float2(accr,acci);
    }
  }
}

// ------------- forward X DFT, slot-split: Fty[(b*32+c)*128+x, J] -> Fm[(b*32+c), s, J]
// grid: nb*Ci*2 (sh=bid&1 -> slots [sh*M1, sh*M1+M1)), block 256.
template<int M1,int M2>
__global__ __launch_bounds__(256,3) void k_fwd_x2(const float* __restrict__ Fty,
                                                  float* __restrict__ Fm, int Ci){
  constexpr int J=2*M2*8;
  constexpr int NIT=(M1*J+255)/256;
  __shared__ float2 tile[32*J];         // <=49152 B
  __shared__ float2 tw128[128];
  int tid=threadIdx.x, bid=blockIdx.x;
  int sh=bid&1; int c=(bid>>1)%Ci; int b=bid/(2*Ci);
  if(tid<128){ float s,cc; sincosf(TWO_PI*tid/128.0f,&s,&cc); tw128[tid]=make_float2(cc,s); }
  float accr[NIT],acci[NIT];
  #pragma unroll
  for(int it=0;it<NIT;it++){accr[it]=0.f;acci[it]=0.f;}
  const float2* base=(const float2*)Fty+((long)(b*32+c)*128)*J;
  for(int xt=0;xt<4;xt++){
    __syncthreads();
    const float2* src=base+(long)xt*32*J;
    for(int idx=tid;idx<32*J;idx+=256) tile[idx]=src[idx];
    __syncthreads();
    #pragma unroll
    for(int it=0;it<NIT;it++){
      int idx=it*256+tid;
      if(idx<M1*J){
        int si=idx/J, j=idx-si*J;
        int km=(sh==0)? si : (si-M1);
        int jj=(km*(xt*32))&127;
        float ar=accr[it], ai=acci[it];
        for(int xl=0;xl<32;xl++){
          float2 w=tw128[jj];
          float2 d=tile[xl*J+j];
          ar+=d.x*w.x+d.y*w.y;
          ai+=d.y*w.x-d.x*w.y;
          jj=(jj+km)&127;
        }
        accr[it]=ar; acci[it]=ai;
      }
    }
  }
  float2* o=(float2*)Fm+(long)(b*32+c)*(2*M1)*J;
  #pragma unroll
  for(int it=0;it<NIT;it++){
    int idx=it*256+tid;
    if(idx<M1*J){
      int si=idx/J, j=idx-si*J;
      int s=sh*M1+si;
      o[(long)s*J+j]=make_float2(accr[it],acci[it]);
    }
  }
}

// ------------- mode mixing (unchanged)
__global__ void k_mix(const float* __restrict__ Fm, const float* __restrict__ w,
                      float* __restrict__ Fm2, int Ci, int Co, int m1, int m2){
  int MC=m1*m2*8;
  int nch=MC/8;
  int bid=blockIdx.x;
  int chunk=bid%nch; int q=(bid/nch)&3; int b=bid/(4*nch);
  int tid=threadIdx.x;
  int M1S=2*m1, M2S=2*m2;
  int J=M2S*8;
  __shared__ float fin[32*16];
  for(int idx=tid;idx<Ci*16;idx+=blockDim.x){
    int i=idx>>4; int r=idx&15; int mll=r>>1; int ri=r&1;
    int mg=chunk*8+mll;
    int mx=mg/(m2*8); int my=(mg>>3)%m2; int kz=mg&7;
    int sx=(q&1)?(m1+mx):mx; int sy=(q&2)?(m2+my):my;
    fin[idx]=Fm[((long)((b*32+i)*M1S+sx)*J+sy*8+kz)*2+ri];
  }
  __syncthreads();
  int ml=tid&7, o=tid>>3;
  int mg=chunk*8+ml;
  int mx=mg/(m2*8); int my=(mg>>3)%m2; int kz=mg&7;
  int sx=(q&1)?(m1+mx):mx; int sy=(q&2)?(m2+my):my;
  int moff=(mx*m2+my)*8+kz;
  const float* wr=w+(long)(q*2)*Ci*Co*MC+o*MC+moff;
  const float* wi=wr+(long)Ci*Co*MC;
  long wstep=(long)Co*MC;
  float re=0.f, im=0.f;
  for(int i=0;i<Ci;i++){
    float ar=fin[i*16+ml*2], ai=fin[i*16+ml*2+1];
    float wrv=wr[i*wstep], wiv=wi[i*wstep];
    re+=ar*wrv-ai*wiv;
    im+=ar*wiv+ai*wrv;
  }
  long oidx=((long)((b*32+o)*M1S+sx)*J+sy*8+kz)*2;
  Fm2[oidx]=re; Fm2[oidx+1]=im;
}

// ------------- FUSED inverse X + inverse Y + inverse T + coalesced float4 RMW + gelu.
// block: 512 threads; grid: nb*Co*16. Fm2: [(b*32+oc)][s1][J] float2.
// LDS: union{Fm2s, Gc} + g1s(pad66) + twiddles  -> <=51.8 KB, 3 blocks/CU.
template<int M>
__global__ __launch_bounds__(512,3) void k_inv_ytx8(const float* __restrict__ Fm2,
                                                    float* h, int Co, int do_gelu){
  constexpr int S1=2*M, S2=2*M;
  constexpr int J=S2*8;
  constexpr int UN=( (S1*J) > (128*33) ? (S1*J) : (128*33) );
  __shared__ __align__(16) float2 uni[UN];     // Fm2s, later Gc
  __shared__ __align__(16) float2 g1s[S2*66];  // [s2][xl*8+kz], row stride 66
  __shared__ float2 tw20[160];
  __shared__ float2 tw128[128];
  int tid=threadIdx.x;
  int bid=blockIdx.x;
  int xg=bid&15, bo=bid>>4; int oc=bo%Co, b=bo/Co;
  int x0=xg*8;
  for(int i=tid;i<160;i+=512){ int t=i>>3,kz=i&7; float s,cc;
    sincosf(TWO_PI*((kz*t)%20)/20.0f,&s,&cc); tw20[i]=make_float2(cc,s); }
  if(tid<128){ float s,cc; sincosf(TWO_PI*tid/128.0f,&s,&cc); tw128[tid]=make_float2(cc,s); }
  // ---- stage Fm2 tile (coalesced)
  float2* Fm2s=uni;
  const float2* src=(const float2*)Fm2+(long)(b*32+oc)*S1*J;
  for(int idx=tid;idx<S1*J;idx+=512) Fm2s[idx]=src[idx];
  __syncthreads();
  // ---- inverse X: lane owns (xl, 2 consecutive j). float4 reads, conflict-free.
  {
    const float4* Fm4=(const float4*)Fm2s;
    float4* g4=(float4*)g1s;
    for(int idx=tid;idx<8*(J/2);idx+=512){
      int xl=idx/(J/2); int j2=idx-xl*(J/2);
      int xgl=x0+xl;
      float re0=0.f,im0=0.f,re1=0.f,im1=0.f;
      int jj=0;
      for(int s=0;s<M;s++){
        float2 w=tw128[jj];
        float4 d=Fm4[s*(J/2)+j2];
        re0+=d.x*w.x-d.y*w.y; im0+=d.x*w.y+d.y*w.x;
        re1+=d.z*w.x-d.w*w.y; im1+=d.z*w.y+d.w*w.x;
        jj=(jj+xgl)&127;
      }
      jj=((128-M)*xgl)&127;
      for(int s=M;s<S1;s++){
        float2 w=tw128[jj];
        float4 d=Fm4[s*(J/2)+j2];
        re0+=d.x*w.x-d.y*w.y; im0+=d.x*w.y+d.y*w.x;
        re1+=d.z*w.x-d.w*w.y; im1+=d.z*w.y+d.w*w.x;
        jj=(jj+xgl)&127;
      }
      int j=2*j2; int s2=j>>3, kz=j&7;            // kz even
      g4[(s2*66+xl*8+kz)>>1]=make_float4(re0,im0,re1,im1);
    }
  }
  __syncthreads();                      // Fm2s dead; uni becomes Gc
  float2* Gc=uni;                       // [y][xlh*8+kz], stride 33
  const float invN=1.0f/(128.0f*128.0f*20.0f);
  float* hb=h+(long)(b*32+oc)*SP3+x0*YT;
  const float4* g4c=(const float4*)g1s;
  for(int half=0;half<2;half++){
    // ---- phase A: inverse-Y into registers; lanes=y, xlh wave-uniform.
    int y=tid&127, xlh=tid>>7;
    int xlg=half*4+xlh;
    float gyr[8],gyi[8];
    #pragma unroll
    for(int kz=0;kz<8;kz++){gyr[kz]=0.f;gyi[kz]=0.f;}
    for(int s=0;s<S2;s++){
      int km=(s<M)?s:(s-S2);
      float2 w=tw128[(km*y)&127];
      int base=(s*66+xlg*8)>>1;
      #pragma unroll
      for(int q=0;q<4;q++){
        float4 d=g4c[base+q];           // wave-uniform broadcast b128
        gyr[2*q]  +=d.x*w.x-d.y*w.y;  gyi[2*q]  +=d.x*w.y+d.y*w.x;
        gyr[2*q+1]+=d.z*w.x-d.w*w.y;  gyi[2*q+1]+=d.z*w.y+d.w*w.x;
      }
    }
    #pragma unroll
    for(int kz=0;kz<8;kz++) Gc[y*33+xlh*8+kz]=make_float2(gyr[kz],gyi[kz]);
    __syncthreads();
    // ---- phase B: inverse-T per float4 task, direct coalesced global RMW.
    for(int task=tid;task<2560;task+=512){
      int r=task/5, q=task-r*5;         // r=(xlh2,y), q = which float4 of the row
      int xlh2=r>>7, yy=r&127;
      float gr[8],gi[8];
      #pragma unroll
      for(int kz=0;kz<8;kz++){ float2 d=Gc[yy*33+xlh2*8+kz]; gr[kz]=d.x; gi[kz]=d.y; }
      float o[4];
      #pragma unroll
      for(int u=0;u<4;u++){
        int t=4*q+u;
        float v=gr[0];
        #pragma unroll
        for(int kz=1;kz<8;kz++){
          float2 w=tw20[t*8+kz];
          v+=2.0f*(gr[kz]*w.x-gi[kz]*w.y);
        }
        o[u]=v*invN;
      }
      float* dp=hb+(long)(half*4+xlh2)*YT+yy*20+4*q;
      float4 hv=*(const float4*)dp;
      float4 ov;
      ov.x=hv.x+o[0]; ov.y=hv.y+o[1]; ov.z=hv.z+o[2]; ov.w=hv.w+o[3];
      if(do_gelu){ov.x=gelu_f(ov.x);ov.y=gelu_f(ov.y);ov.z=gelu_f(ov.z);ov.w=gelu_f(ov.w);}
      *(float4*)dp=ov;
    }
    __syncthreads();                    // Gc reused next half
  }
}

// ------------- pointwise conv IN-PLACE, float2 point-pairs, float4 weight broadcasts.
template<int CO>
__global__ __launch_bounds__(256,4) void k_pconv2(float* h, const float* __restrict__ w,
                                                  const float* __restrict__ bias, int Ci){
  __shared__ __align__(16) float wt[32*CO];   // [i][o]
  __shared__ float bl[CO];
  int tid=threadIdx.x;
  for(int idx=tid;idx<Ci*CO;idx+=256){int i=idx/CO,o=idx-i*CO; wt[idx]=w[o*Ci+i];}
  if(tid<CO) bl[tid]=bias[tid];
  __syncthreads();
  long p=(long)blockIdx.x*512+tid*2;   // points p, p+1 (contiguous pair)
  int b=(int)(p/SP3); int sp=(int)(p-(long)b*SP3);
  float* hb=h+(long)b*32*SP3+sp;
  float acc0[CO],acc1[CO];
  #pragma unroll
  for(int o=0;o<CO;o++){acc0[o]=bl[o];acc1[o]=bl[o];}
  for(int i=0;i<Ci;i++){
    float2 v=*(const float2*)&hb[(long)i*SP3];
    const float4* wc=(const float4*)&wt[i*CO];
    #pragma unroll
    for(int o4=0;o4<CO/4;o4++){
      float4 ww=wc[o4];
      acc0[4*o4+0]+=v.x*ww.x; acc0[4*o4+1]+=v.x*ww.y;
      acc0[4*o4+2]+=v.x*ww.z; acc0[4*o4+3]+=v.x*ww.w;
      acc1[4*o4+0]+=v.y*ww.x; acc1[4*o4+1]+=v.y*ww.y;
      acc1[4*o4+2]+=v.y*ww.z; acc1[4*o4+3]+=v.y*ww.w;
    }
  }
  #pragma unroll
  for(int o=0;o<CO;o++){
    *(float2*)&hb[(long)o*SP3]=make_float2(acc0[o],acc1[o]);
  }
}

// ------------- prep: transpose w1 (32x128 [i][jj]) -> w1t (128x32 [jj][i])
__global__ void k_prep_w1t(const float* __restrict__ w1, float* __restrict__ w1t){
  int idx=blockIdx.x*256+threadIdx.x;
  if(idx<4096){ int jj=idx>>5, i=idx&31; w1t[idx]=w1[i*128+jj]; }
}

// ------------- head, scalar-operand weights: fc1(32->128)+gelu, fc2(128->3).
__global__ __launch_bounds__(256,3) void k_head_s(const float* __restrict__ h,
                       const float* __restrict__ w1t, const float* __restrict__ b1,
                       const float* __restrict__ w2, const float* __restrict__ b2,
                       float* __restrict__ out){
  long p=(long)blockIdx.x*512+threadIdx.x;
  int b=(int)(p/SP3); int sp=(int)(p-(long)b*SP3);
  const float* hb=h+(long)b*32*SP3+sp;
  float hv0[32],hv1[32];
  #pragma unroll
  for(int i=0;i<32;i++){hv0[i]=hb[(long)i*SP3]; hv1[i]=hb[(long)i*SP3+256];}
  float a00=b2[0],a01=b2[1],a02=b2[2];
  float a10=a00,a11=a01,a12=a02;
  for(int jj=0;jj<128;jj++){
    const float* wc=w1t+jj*32;
    float u0=b1[jj], u1=u0;
    #pragma unroll
    for(int q=0;q<32;q++){
      float ww=wc[q];
      u0+=hv0[q]*ww;
      u1+=hv1[q]*ww;
    }
    u0=gelu_f(u0); u1=gelu_f(u1);
    float w20=w2[jj*3], w21=w2[jj*3+1], w22=w2[jj*3+2];
    a00+=u0*w20; a01+=u0*w21; a02+=u0*w22;
    a10+=u1*w20; a11+=u1*w21; a12+=u1*w22;
  }
  float* op=out+p*3;
  op[0]=a00; op[1]=a01; op[2]=a02;
  op=out+(p+256)*3;
  op[0]=a10; op[1]=a11; op[2]=a12;
}

// ------------- head fallback (LDS weights) for the low-workspace path
__global__ __launch_bounds__(256,4) void k_head2(const float* __restrict__ h,
                       const float* __restrict__ w1, const float* __restrict__ b1,
                       const float* __restrict__ w2, const float* __restrict__ b2,
                       float* __restrict__ out){
  __shared__ __align__(16) float w1t[128*32];   // [jj][i]
  __shared__ float b1l[128];
  __shared__ __align__(16) float4 w2l[128];
  __shared__ float b2l[3];
  int tid=threadIdx.x;
  for(int idx=tid;idx<4096;idx+=256){int jj=idx>>5,i=idx&31; w1t[idx]=w1[i*128+jj];}
  if(tid<128){b1l[tid]=b1[tid]; w2l[tid]=make_float4(w2[tid*3],w2[tid*3+1],w2[tid*3+2],0.f);}
  if(tid<3) b2l[tid]=b2[tid];
  __syncthreads();
  long p=(long)blockIdx.x*512+tid;
  int b=(int)(p/SP3); int sp=(int)(p-(long)b*SP3);
  const float* hb=h+(long)b*32*SP3+sp;
  float hv0[32],hv1[32];
  #pragma unroll
  for(int i=0;i<32;i++){hv0[i]=hb[(long)i*SP3]; hv1[i]=hb[(long)i*SP3+256];}
  float a00=b2l[0],a01=b2l[1],a02=b2l[2];
  float a10=a00,a11=a01,a12=a02;
  for(int jj=0;jj<128;jj++){
    const float4* wc=(const float4*)&w1t[jj*32];
    float u0=b1l[jj], u1=u0;
    #pragma unroll
    for(int q=0;q<8;q++){
      float4 ww=wc[q];
      u0+=hv0[4*q]*ww.x+hv0[4*q+1]*ww.y+hv0[4*q+2]*ww.z+hv0[4*q+3]*ww.w;
      u1+=hv1[4*q]*ww.x+hv1[4*q+1]*ww.y+hv1[4*q+2]*ww.z+hv1[4*q+3]*ww.w;
    }
    u0=gelu_f(u0); u1=gelu_f(u1);
    float4 w2v=w2l[jj];
    a00+=u0*w2v.x; a01+=u0*w2v.y; a02+=u0*w2v.z;
    a10+=u1*w2v.x; a11+=u1*w2v.y; a12+=u1*w2v.z;
  }
  float* op=out+p*3;
  op[0]=a00; op[1]=a01; op[2]=a02;
  op=out+(p+256)*3;
  op[0]=a10; op[1]=a11; op[2]=a12;
}

extern "C" void kernel_launch(void* const* d_in, const int* in_sizes, int n_in,
                              void* d_out, int out_size, void* d_ws, size_t ws_size,
                              hipStream_t stream){
  (void)in_sizes; (void)n_in; (void)out_size;
  const float* x    =(const float*)d_in[0];
  const float* fc0w =(const float*)d_in[1];
  const float* fc0b =(const float*)d_in[2];
  const float* sw[4]={(const float*)d_in[3],(const float*)d_in[6],(const float*)d_in[9],(const float*)d_in[12]};
  const float* cw[4]={(const float*)d_in[4],(const float*)d_in[7],(const float*)d_in[10],(const float*)d_in[13]};
  const float* cb[4]={(const float*)d_in[5],(const float*)d_in[8],(const float*)d_in[11],(const float*)d_in[14]};
  const float* fc1w =(const float*)d_in[15];
  const float* fc1b =(const float*)d_in[16];
  const float* fc2w =(const float*)d_in[17];
  const float* fc2b =(const float*)d_in[18];
  float* out=(float*)d_out;
  float* ws=(float*)d_ws;

  const long H_FLOATS   = 41943040L;            // 4*32*327680 (168 MB)
  const long FTY_FULL   = 6291456L;             // 4*32*128*192*2
  const long FM_FULL    = 1179648L;             // 4*32*24*192*2
  const long NEED_FULL  = H_FLOATS + FTY_FULL + 2*FM_FULL;

  float* h = ws;
  bool full = (ws_size >= (size_t)NEED_FULL*4);

  const int LAY[5]={20,24,24,32,32};
  const int M1A[4]={8,8,12,12};

  k_fc0<<<5120,256,0,stream>>>(x,fc0w,fc0b,h);

  for(int L=0;L<4;L++){
    int Ci=LAY[L], Co=LAY[L+1], m1=M1A[L], m2=M1A[L];
    int nch=m1*m2;
    long FM_B=(long)32*(2*m1)*(2*m2*8)*2;

    if(full){
      float* Fty=ws+H_FLOATS;
      float* Fm =ws+H_FLOATS+FTY_FULL;
      float* Fm2=ws+H_FLOATS+FTY_FULL+FM_FULL;
      if(m1==8)  k_fwd_ty8<8> <<<4*Ci*16,512,0,stream>>>(h,Fty,Ci);
      else       k_fwd_ty8<12><<<4*Ci*16,512,0,stream>>>(h,Fty,Ci);
      if(m1==8)  k_fwd_x2<8,8>  <<<4*Ci*2,256,0,stream>>>(Fty,Fm,Ci);
      else       k_fwd_x2<12,12><<<4*Ci*2,256,0,stream>>>(Fty,Fm,Ci);
      k_mix<<<4*4*nch,Co*8,0,stream>>>(Fm,sw[L],Fm2,Ci,Co,m1,m2);
      if(Co==24) k_pconv2<24><<<2560,256,0,stream>>>(h,cw[L],cb[L],Ci);
      else       k_pconv2<32><<<2560,256,0,stream>>>(h,cw[L],cb[L],Ci);
      if(m1==8)  k_inv_ytx8<8> <<<4*Co*16,512,0,stream>>>(Fm2,h,Co,(L!=3)?1:0);
      else       k_inv_ytx8<12><<<4*Co*16,512,0,stream>>>(Fm2,h,Co,(L!=3)?1:0);
    } else {
      // scratch lives in d_out (rewritten entirely by head at the end)
      float* Fty=out;                 // <= 1,572,864 floats
      float* Fm =out+1572864;         // <=   294,912 floats
      float* Fm2=out+1867776;         // <= 1,179,648 floats (per-b strided)
      for(int b=0;b<4;b++){
        float* hbp=h+(long)b*32*SP3;
        if(m1==8)  k_fwd_ty8<8> <<<Ci*16,512,0,stream>>>(hbp,Fty,Ci);
        else       k_fwd_ty8<12><<<Ci*16,512,0,stream>>>(hbp,Fty,Ci);
        if(m1==8)  k_fwd_x2<8,8>  <<<Ci*2,256,0,stream>>>(Fty,Fm,Ci);
        else       k_fwd_x2<12,12><<<Ci*2,256,0,stream>>>(Fty,Fm,Ci);
        k_mix<<<4*nch,Co*8,0,stream>>>(Fm,sw[L],Fm2+b*FM_B,Ci,Co,m1,m2);
      }
      if(Co==24) k_pconv2<24><<<2560,256,0,stream>>>(h,cw[L],cb[L],Ci);
      else       k_pconv2<32><<<2560,256,0,stream>>>(h,cw[L],cb[L],Ci);
      for(int b=0;b<4;b++){
        float* hbp=h+(long)b*32*SP3;
        if(m1==8)  k_inv_ytx8<8> <<<Co*16,512,0,stream>>>(Fm2+b*FM_B,hbp,Co,(L!=3)?1:0);
        else       k_inv_ytx8<12><<<Co*16,512,0,stream>>>(Fm2+b*FM_B,hbp,Co,(L!=3)?1:0);
      }
    }
  }
  if(full){
    float* w1t=ws+H_FLOATS+FTY_FULL;    // Fm region, dead by now
    k_prep_w1t<<<16,256,0,stream>>>(fc1w,w1t);
    k_head_s<<<2560,256,0,stream>>>(h,w1t,fc1b,fc2w,fc2b,out);
  } else {
    k_head2<<<2560,256,0,stream>>>(h,fc1w,fc1b,fc2w,fc2b,out);
  }
}

// Round 8
// 1841.863 us; speedup vs baseline: 1.1976x; 1.1976x over previous
//
#include <hip/hip_runtime.h>

#define TWO_PI 6.2831853071795864769f
#define SP3 327680      // 128*128*20
#define YT 2560         // 128*20

static __device__ __forceinline__ float gelu_f(float u){
  return 0.5f*u*(1.0f+erff(u*0.7071067811865475f));
}

// ---------------- fc0: x(B,X,Y,T,5) @ (5,20) + b -> h(B,32stride,X,Y,T), 20 ch ----
__global__ void k_fc0(const float* __restrict__ x, const float* __restrict__ w,
                      const float* __restrict__ bias, float* __restrict__ h){
  __shared__ float wl[100], bl[20];
  int tid=threadIdx.x;
  if(tid<100) wl[tid]=w[tid];
  if(tid<20) bl[tid]=bias[tid];
  __syncthreads();
  int p=blockIdx.x*256+tid;          // 0..1310719
  int b=p/SP3, sp=p-b*SP3;
  const float* xp=x+(long)p*5;
  float xi[5];
  #pragma unroll
  for(int i=0;i<5;i++) xi[i]=xp[i];
  float* hb=h+(long)(b*32)*SP3+sp;
  #pragma unroll
  for(int c=0;c<20;c++){
    float a=bl[c];
    #pragma unroll
    for(int i=0;i<5;i++) a+=xi[i]*wl[i*20+c];
    hb[(long)c*SP3]=a;
  }
}

// ------------- forward T+Y DFT over 8-x slabs. Direct global float4 row reads.
// Y-DFT uses conjugate-pair slots: one Gc read + one tw read feed slots s and 2*M2-s.
// block: 512 threads; grid: nb*Ci*16. out: Fty[(b*32+c)*128+x][slot2*8+kz] float2.
template<int M2>
__global__ __launch_bounds__(512,3) void k_fwd_ty8(const float* __restrict__ h,
                                                   float* __restrict__ Fty, int Ci){
  constexpr int J=2*M2*8;
  __shared__ float2 Gc[128*33];         // 33792 B, [y][col=xl*8+kz], pad 33
  __shared__ __align__(16) float2 tw20[160];
  __shared__ float2 tw128[128];
  int tid=threadIdx.x;
  int bid=blockIdx.x;
  int xg=bid&15, bc=bid>>4; int c=bc%Ci, b=bc/Ci;
  int x0=xg*8;
  for(int i=tid;i<160;i+=512){ int t=i>>3,kz=i&7; float s,cc;
    sincosf(TWO_PI*((kz*t)%20)/20.0f,&s,&cc); tw20[i]=make_float2(cc,s); }
  if(tid<128){ float s,cc; sincosf(TWO_PI*tid/128.0f,&s,&cc); tw128[tid]=make_float2(cc,s); }
  __syncthreads();
  const float* hb=h+(long)(b*32+c)*SP3+x0*YT;
  float2* outp=(float2*)Fty+((long)(b*32+c)*128+x0)*J;
  const float4* twp=(const float4*)tw20;   // [t*4+q] -> (c,s) for kz=2q,2q+1

  for(int half=0;half<2;half++){
    if(half) __syncthreads();             // protect Gc from prev half readers
    // ---- T-DFT: one row per thread, direct global float4 reads
    {
      int y=tid&127, xl=tid>>7;
      const float* rp=hb+(half*4+xl)*YT+y*20;
      float4 r0=*(const float4*)(rp);
      float4 r1=*(const float4*)(rp+4);
      float4 r2=*(const float4*)(rp+8);
      float4 r3=*(const float4*)(rp+12);
      float4 r4=*(const float4*)(rp+16);
      float row[20]={r0.x,r0.y,r0.z,r0.w, r1.x,r1.y,r1.z,r1.w, r2.x,r2.y,r2.z,r2.w,
                     r3.x,r3.y,r3.z,r3.w, r4.x,r4.y,r4.z,r4.w};
      float re[8],im[8];
      #pragma unroll
      for(int kz=0;kz<8;kz++){re[kz]=0.f;im[kz]=0.f;}
      #pragma unroll
      for(int t=0;t<20;t++){
        float v=row[t];
        #pragma unroll
        for(int q=0;q<4;q++){
          float4 w=twp[t*4+q];
          re[2*q]  +=v*w.x; im[2*q]  -=v*w.y;
          re[2*q+1]+=v*w.z; im[2*q+1]-=v*w.w;
        }
      }
      #pragma unroll
      for(int kz=0;kz<8;kz++) Gc[y*33+xl*8+kz]=make_float2(re[kz],im[kz]);
    }
    __syncthreads();
    // ---- Y-DFT, conjugate-paired: item=(sp,col), sp in [0,M2]
    for(int ip=tid;ip<(M2+1)*32;ip+=512){
      int col=ip&31, sp=ip>>5;
      float a1r=0.f,a1i=0.f,a2r=0.f,a2i=0.f;
      int jj=0;
      for(int y=0;y<128;y++){
        float2 w=tw128[jj];
        float2 d=Gc[y*33+col];
        float tr=d.x*w.x, ts=d.y*w.y, ur=d.y*w.x, us=d.x*w.y;
        a1r+=tr+ts; a1i+=ur-us;          // slot sp      (km=+sp)
        a2r+=tr-ts; a2i+=ur+us;          // slot 2M2-sp  (km=-sp)
        jj=(jj+sp)&127;
      }
      int xl=col>>3, kz=col&7;
      long rowoff=(long)(half*4+xl)*J;
      if(sp<M2) outp[rowoff+sp*8+kz]=make_float2(a1r,a1i);
      if(sp>=1) outp[rowoff+(2*M2-sp)*8+kz]=make_float2(a2r,a2i);
    }
  }
}

// ------------- forward X DFT, slot-split: Fty[(b*32+c)*128+x, J] -> Fm[(b*32+c), s, J]
// grid: nb*Ci*2 (sh=bid&1 -> slots [sh*M1, sh*M1+M1)), block 256.
template<int M1,int M2>
__global__ __launch_bounds__(256,3) void k_fwd_x2(const float* __restrict__ Fty,
                                                  float* __restrict__ Fm, int Ci){
  constexpr int J=2*M2*8;
  constexpr int NIT=(M1*J+255)/256;
  __shared__ float2 tile[32*J];         // <=49152 B
  __shared__ float2 tw128[128];
  int tid=threadIdx.x, bid=blockIdx.x;
  int sh=bid&1; int c=(bid>>1)%Ci; int b=bid/(2*Ci);
  if(tid<128){ float s,cc; sincosf(TWO_PI*tid/128.0f,&s,&cc); tw128[tid]=make_float2(cc,s); }
  float accr[NIT],acci[NIT];
  #pragma unroll
  for(int it=0;it<NIT;it++){accr[it]=0.f;acci[it]=0.f;}
  const float2* base=(const float2*)Fty+((long)(b*32+c)*128)*J;
  for(int xt=0;xt<4;xt++){
    __syncthreads();
    const float2* src=base+(long)xt*32*J;
    for(int idx=tid;idx<32*J;idx+=256) tile[idx]=src[idx];
    __syncthreads();
    #pragma unroll
    for(int it=0;it<NIT;it++){
      int idx=it*256+tid;
      if(idx<M1*J){
        int si=idx/J, j=idx-si*J;
        int km=(sh==0)? si : (si-M1);
        int jj=(km*(xt*32))&127;
        float ar=accr[it], ai=acci[it];
        for(int xl=0;xl<32;xl++){
          float2 w=tw128[jj];
          float2 d=tile[xl*J+j];
          ar+=d.x*w.x+d.y*w.y;
          ai+=d.y*w.x-d.x*w.y;
          jj=(jj+km)&127;
        }
        accr[it]=ar; acci[it]=ai;
      }
    }
  }
  float2* o=(float2*)Fm+(long)(b*32+c)*(2*M1)*J;
  #pragma unroll
  for(int it=0;it<NIT;it++){
    int idx=it*256+tid;
    if(idx<M1*J){
      int si=idx/J, j=idx-si*J;
      int s=sh*M1+si;
      o[(long)s*J+j]=make_float2(accr[it],acci[it]);
    }
  }
}

// ------------- mode mixing (unchanged)
__global__ void k_mix(const float* __restrict__ Fm, const float* __restrict__ w,
                      float* __restrict__ Fm2, int Ci, int Co, int m1, int m2){
  int MC=m1*m2*8;
  int nch=MC/8;
  int bid=blockIdx.x;
  int chunk=bid%nch; int q=(bid/nch)&3; int b=bid/(4*nch);
  int tid=threadIdx.x;
  int M1S=2*m1, M2S=2*m2;
  int J=M2S*8;
  __shared__ float fin[32*16];
  for(int idx=tid;idx<Ci*16;idx+=blockDim.x){
    int i=idx>>4; int r=idx&15; int mll=r>>1; int ri=r&1;
    int mg=chunk*8+mll;
    int mx=mg/(m2*8); int my=(mg>>3)%m2; int kz=mg&7;
    int sx=(q&1)?(m1+mx):mx; int sy=(q&2)?(m2+my):my;
    fin[idx]=Fm[((long)((b*32+i)*M1S+sx)*J+sy*8+kz)*2+ri];
  }
  __syncthreads();
  int ml=tid&7, o=tid>>3;
  int mg=chunk*8+ml;
  int mx=mg/(m2*8); int my=(mg>>3)%m2; int kz=mg&7;
  int sx=(q&1)?(m1+mx):mx; int sy=(q&2)?(m2+my):my;
  int moff=(mx*m2+my)*8+kz;
  const float* wr=w+(long)(q*2)*Ci*Co*MC+o*MC+moff;
  const float* wi=wr+(long)Ci*Co*MC;
  long wstep=(long)Co*MC;
  float re=0.f, im=0.f;
  for(int i=0;i<Ci;i++){
    float ar=fin[i*16+ml*2], ai=fin[i*16+ml*2+1];
    float wrv=wr[i*wstep], wiv=wi[i*wstep];
    re+=ar*wrv-ai*wiv;
    im+=ar*wiv+ai*wrv;
  }
  long oidx=((long)((b*32+o)*M1S+sx)*J+sy*8+kz)*2;
  Fm2[oidx]=re; Fm2[oidx+1]=im;
}

// ------------- FUSED inverse X + inverse Y + inverse T + coalesced float4 RMW + gelu.
// block: 512 threads; grid: nb*Co*16. Fm2: [(b*32+oc)][s1][J] float2.
// tw20p padded to stride 9 so per-lane t (t=4q+u) spreads banks: (8q)&31 -> 2-way max.
template<int M>
__global__ __launch_bounds__(512,3) void k_inv_ytx8(const float* __restrict__ Fm2,
                                                    float* h, int Co, int do_gelu){
  constexpr int S1=2*M, S2=2*M;
  constexpr int J=S2*8;
  constexpr int UN=( (S1*J) > (128*33) ? (S1*J) : (128*33) );
  __shared__ __align__(16) float2 uni[UN];     // Fm2s, later Gc
  __shared__ __align__(16) float2 g1s[S2*66];  // [s2][xl*8+kz], row stride 66
  __shared__ float2 tw20p[20*9];               // padded [t*9+kz]
  __shared__ float2 tw128[128];
  int tid=threadIdx.x;
  int bid=blockIdx.x;
  int xg=bid&15, bo=bid>>4; int oc=bo%Co, b=bo/Co;
  int x0=xg*8;
  for(int i=tid;i<160;i+=512){ int t=i>>3,kz=i&7; float s,cc;
    sincosf(TWO_PI*((kz*t)%20)/20.0f,&s,&cc); tw20p[t*9+kz]=make_float2(cc,s); }
  if(tid<128){ float s,cc; sincosf(TWO_PI*tid/128.0f,&s,&cc); tw128[tid]=make_float2(cc,s); }
  // ---- stage Fm2 tile (coalesced)
  float2* Fm2s=uni;
  const float2* src=(const float2*)Fm2+(long)(b*32+oc)*S1*J;
  for(int idx=tid;idx<S1*J;idx+=512) Fm2s[idx]=src[idx];
  __syncthreads();
  // ---- inverse X: lane owns (xl, 2 consecutive j). float4 reads, conflict-free.
  {
    const float4* Fm4=(const float4*)Fm2s;
    float4* g4=(float4*)g1s;
    for(int idx=tid;idx<8*(J/2);idx+=512){
      int xl=idx/(J/2); int j2=idx-xl*(J/2);
      int xgl=x0+xl;
      float re0=0.f,im0=0.f,re1=0.f,im1=0.f;
      int jj=0;
      for(int s=0;s<M;s++){
        float2 w=tw128[jj];
        float4 d=Fm4[s*(J/2)+j2];
        re0+=d.x*w.x-d.y*w.y; im0+=d.x*w.y+d.y*w.x;
        re1+=d.z*w.x-d.w*w.y; im1+=d.z*w.y+d.w*w.x;
        jj=(jj+xgl)&127;
      }
      jj=((128-M)*xgl)&127;
      for(int s=M;s<S1;s++){
        float2 w=tw128[jj];
        float4 d=Fm4[s*(J/2)+j2];
        re0+=d.x*w.x-d.y*w.y; im0+=d.x*w.y+d.y*w.x;
        re1+=d.z*w.x-d.w*w.y; im1+=d.z*w.y+d.w*w.x;
        jj=(jj+xgl)&127;
      }
      int j=2*j2; int s2=j>>3, kz=j&7;            // kz even
      g4[(s2*66+xl*8+kz)>>1]=make_float4(re0,im0,re1,im1);
    }
  }
  __syncthreads();                      // Fm2s dead; uni becomes Gc
  float2* Gc=uni;                       // [y][xlh*8+kz], stride 33
  const float invN=1.0f/(128.0f*128.0f*20.0f);
  float* hb=h+(long)(b*32+oc)*SP3+x0*YT;
  const float4* g4c=(const float4*)g1s;
  for(int half=0;half<2;half++){
    // ---- phase A: inverse-Y into registers; lanes=y, xlh wave-uniform.
    int y=tid&127, xlh=tid>>7;
    int xlg=half*4+xlh;
    float gyr[8],gyi[8];
    #pragma unroll
    for(int kz=0;kz<8;kz++){gyr[kz]=0.f;gyi[kz]=0.f;}
    for(int s=0;s<S2;s++){
      int km=(s<M)?s:(s-S2);
      float2 w=tw128[(km*y)&127];
      int base=(s*66+xlg*8)>>1;
      #pragma unroll
      for(int q=0;q<4;q++){
        float4 d=g4c[base+q];           // wave-uniform broadcast b128
        gyr[2*q]  +=d.x*w.x-d.y*w.y;  gyi[2*q]  +=d.x*w.y+d.y*w.x;
        gyr[2*q+1]+=d.z*w.x-d.w*w.y;  gyi[2*q+1]+=d.z*w.y+d.w*w.x;
      }
    }
    #pragma unroll
    for(int kz=0;kz<8;kz++) Gc[y*33+xlh*8+kz]=make_float2(gyr[kz],gyi[kz]);
    __syncthreads();
    // ---- phase B: inverse-T per float4 task, direct coalesced global RMW.
    for(int task=tid;task<2560;task+=512){
      int r=task/5, q=task-r*5;         // r=(xlh2,y), q = which float4 of the row
      int xlh2=r>>7, yy=r&127;
      float gr[8],gi[8];
      #pragma unroll
      for(int kz=0;kz<8;kz++){ float2 d=Gc[yy*33+xlh2*8+kz]; gr[kz]=d.x; gi[kz]=d.y; }
      float o[4];
      #pragma unroll
      for(int u=0;u<4;u++){
        int t=4*q+u;
        float v=gr[0];
        #pragma unroll
        for(int kz=1;kz<8;kz++){
          float2 w=tw20p[t*9+kz];
          v+=2.0f*(gr[kz]*w.x-gi[kz]*w.y);
        }
        o[u]=v*invN;
      }
      float* dp=hb+(long)(half*4+xlh2)*YT+yy*20+4*q;
      float4 hv=*(const float4*)dp;
      float4 ov;
      ov.x=hv.x+o[0]; ov.y=hv.y+o[1]; ov.z=hv.z+o[2]; ov.w=hv.w+o[3];
      if(do_gelu){ov.x=gelu_f(ov.x);ov.y=gelu_f(ov.y);ov.z=gelu_f(ov.z);ov.w=gelu_f(ov.w);}
      *(float4*)dp=ov;
    }
    __syncthreads();                    // Gc reused next half
  }
}

// ------------- pointwise conv IN-PLACE, float2 point-pairs, float4 weight broadcasts.
template<int CO>
__global__ __launch_bounds__(256,4) void k_pconv2(float* h, const float* __restrict__ w,
                                                  const float* __restrict__ bias, int Ci){
  __shared__ __align__(16) float wt[32*CO];   // [i][o]
  __shared__ float bl[CO];
  int tid=threadIdx.x;
  for(int idx=tid;idx<Ci*CO;idx+=256){int i=idx/CO,o=idx-i*CO; wt[idx]=w[o*Ci+i];}
  if(tid<CO) bl[tid]=bias[tid];
  __syncthreads();
  long p=(long)blockIdx.x*512+tid*2;   // points p, p+1 (contiguous pair)
  int b=(int)(p/SP3); int sp=(int)(p-(long)b*SP3);
  float* hb=h+(long)b*32*SP3+sp;
  float acc0[CO],acc1[CO];
  #pragma unroll
  for(int o=0;o<CO;o++){acc0[o]=bl[o];acc1[o]=bl[o];}
  for(int i=0;i<Ci;i++){
    float2 v=*(const float2*)&hb[(long)i*SP3];
    const float4* wc=(const float4*)&wt[i*CO];
    #pragma unroll
    for(int o4=0;o4<CO/4;o4++){
      float4 ww=wc[o4];
      acc0[4*o4+0]+=v.x*ww.x; acc0[4*o4+1]+=v.x*ww.y;
      acc0[4*o4+2]+=v.x*ww.z; acc0[4*o4+3]+=v.x*ww.w;
      acc1[4*o4+0]+=v.y*ww.x; acc1[4*o4+1]+=v.y*ww.y;
      acc1[4*o4+2]+=v.y*ww.z; acc1[4*o4+3]+=v.y*ww.w;
    }
  }
  #pragma unroll
  for(int o=0;o<CO;o++){
    *(float2*)&hb[(long)o*SP3]=make_float2(acc0[o],acc1[o]);
  }
}

// ------------- prep: transpose w1 (32x128 [i][jj]) -> w1t (128x32 [jj][i])
__global__ void k_prep_w1t(const float* __restrict__ w1, float* __restrict__ w1t){
  int idx=blockIdx.x*256+threadIdx.x;
  if(idx<4096){ int jj=idx>>5, i=idx&31; w1t[idx]=w1[i*128+jj]; }
}

// ------------- head, scalar-operand weights: fc1(32->128)+gelu, fc2(128->3).
__global__ __launch_bounds__(256,3) void k_head_s(const float* __restrict__ h,
                       const float* __restrict__ w1t, const float* __restrict__ b1,
                       const float* __restrict__ w2, const float* __restrict__ b2,
                       float* __restrict__ out){
  long p=(long)blockIdx.x*512+threadIdx.x;
  int b=(int)(p/SP3); int sp=(int)(p-(long)b*SP3);
  const float* hb=h+(long)b*32*SP3+sp;
  float hv0[32],hv1[32];
  #pragma unroll
  for(int i=0;i<32;i++){hv0[i]=hb[(long)i*SP3]; hv1[i]=hb[(long)i*SP3+256];}
  float a00=b2[0],a01=b2[1],a02=b2[2];
  float a10=a00,a11=a01,a12=a02;
  for(int jj=0;jj<128;jj++){
    const float* wc=w1t+jj*32;
    float u0=b1[jj], u1=u0;
    #pragma unroll
    for(int q=0;q<32;q++){
      float ww=wc[q];
      u0+=hv0[q]*ww;
      u1+=hv1[q]*ww;
    }
    u0=gelu_f(u0); u1=gelu_f(u1);
    float w20=w2[jj*3], w21=w2[jj*3+1], w22=w2[jj*3+2];
    a00+=u0*w20; a01+=u0*w21; a02+=u0*w22;
    a10+=u1*w20; a11+=u1*w21; a12+=u1*w22;
  }
  float* op=out+p*3;
  op[0]=a00; op[1]=a01; op[2]=a02;
  op=out+(p+256)*3;
  op[0]=a10; op[1]=a11; op[2]=a12;
}

// ------------- head fallback (LDS weights) for the low-workspace path
__global__ __launch_bounds__(256,4) void k_head2(const float* __restrict__ h,
                       const float* __restrict__ w1, const float* __restrict__ b1,
                       const float* __restrict__ w2, const float* __restrict__ b2,
                       float* __restrict__ out){
  __shared__ __align__(16) float w1t[128*32];   // [jj][i]
  __shared__ float b1l[128];
  __shared__ __align__(16) float4 w2l[128];
  __shared__ float b2l[3];
  int tid=threadIdx.x;
  for(int idx=tid;idx<4096;idx+=256){int jj=idx>>5,i=idx&31; w1t[idx]=w1[i*128+jj];}
  if(tid<128){b1l[tid]=b1[tid]; w2l[tid]=make_float4(w2[tid*3],w2[tid*3+1],w2[tid*3+2],0.f);}
  if(tid<3) b2l[tid]=b2[tid];
  __syncthreads();
  long p=(long)blockIdx.x*512+tid;
  int b=(int)(p/SP3); int sp=(int)(p-(long)b*SP3);
  const float* hb=h+(long)b*32*SP3+sp;
  float hv0[32],hv1[32];
  #pragma unroll
  for(int i=0;i<32;i++){hv0[i]=hb[(long)i*SP3]; hv1[i]=hb[(long)i*SP3+256];}
  float a00=b2l[0],a01=b2l[1],a02=b2l[2];
  float a10=a00,a11=a01,a12=a02;
  for(int jj=0;jj<128;jj++){
    const float4* wc=(const float4*)&w1t[jj*32];
    float u0=b1l[jj], u1=u0;
    #pragma unroll
    for(int q=0;q<8;q++){
      float4 ww=wc[q];
      u0+=hv0[4*q]*ww.x+hv0[4*q+1]*ww.y+hv0[4*q+2]*ww.z+hv0[4*q+3]*ww.w;
      u1+=hv1[4*q]*ww.x+hv1[4*q+1]*ww.y+hv1[4*q+2]*ww.z+hv1[4*q+3]*ww.w;
    }
    u0=gelu_f(u0); u1=gelu_f(u1);
    float4 w2v=w2l[jj];
    a00+=u0*w2v.x; a01+=u0*w2v.y; a02+=u0*w2v.z;
    a10+=u1*w2v.x; a11+=u1*w2v.y; a12+=u1*w2v.z;
  }
  float* op=out+p*3;
  op[0]=a00; op[1]=a01; op[2]=a02;
  op=out+(p+256)*3;
  op[0]=a10; op[1]=a11; op[2]=a12;
}

extern "C" void kernel_launch(void* const* d_in, const int* in_sizes, int n_in,
                              void* d_out, int out_size, void* d_ws, size_t ws_size,
                              hipStream_t stream){
  (void)in_sizes; (void)n_in; (void)out_size;
  const float* x    =(const float*)d_in[0];
  const float* fc0w =(const float*)d_in[1];
  const float* fc0b =(const float*)d_in[2];
  const float* sw[4]={(const float*)d_in[3],(const float*)d_in[6],(const float*)d_in[9],(const float*)d_in[12]};
  const float* cw[4]={(const float*)d_in[4],(const float*)d_in[7],(const float*)d_in[10],(const float*)d_in[13]};
  const float* cb[4]={(const float*)d_in[5],(const float*)d_in[8],(const float*)d_in[11],(const float*)d_in[14]};
  const float* fc1w =(const float*)d_in[15];
  const float* fc1b =(const float*)d_in[16];
  const float* fc2w =(const float*)d_in[17];
  const float* fc2b =(const float*)d_in[18];
  float* out=(float*)d_out;
  float* ws=(float*)d_ws;

  const long H_FLOATS   = 41943040L;            // 4*32*327680 (168 MB)
  const long FTY_FULL   = 6291456L;             // 4*32*128*192*2
  const long FM_FULL    = 1179648L;             // 4*32*24*192*2
  const long NEED_FULL  = H_FLOATS + FTY_FULL + 2*FM_FULL;

  float* h = ws;
  bool full = (ws_size >= (size_t)NEED_FULL*4);

  const int LAY[5]={20,24,24,32,32};
  const int M1A[4]={8,8,12,12};

  k_fc0<<<5120,256,0,stream>>>(x,fc0w,fc0b,h);

  for(int L=0;L<4;L++){
    int Ci=LAY[L], Co=LAY[L+1], m1=M1A[L], m2=M1A[L];
    int nch=m1*m2;
    long FM_B=(long)32*(2*m1)*(2*m2*8)*2;

    if(full){
      float* Fty=ws+H_FLOATS;
      float* Fm =ws+H_FLOATS+FTY_FULL;
      float* Fm2=ws+H_FLOATS+FTY_FULL+FM_FULL;
      if(m1==8)  k_fwd_ty8<8> <<<4*Ci*16,512,0,stream>>>(h,Fty,Ci);
      else       k_fwd_ty8<12><<<4*Ci*16,512,0,stream>>>(h,Fty,Ci);
      if(m1==8)  k_fwd_x2<8,8>  <<<4*Ci*2,256,0,stream>>>(Fty,Fm,Ci);
      else       k_fwd_x2<12,12><<<4*Ci*2,256,0,stream>>>(Fty,Fm,Ci);
      k_mix<<<4*4*nch,Co*8,0,stream>>>(Fm,sw[L],Fm2,Ci,Co,m1,m2);
      if(Co==24) k_pconv2<24><<<2560,256,0,stream>>>(h,cw[L],cb[L],Ci);
      else       k_pconv2<32><<<2560,256,0,stream>>>(h,cw[L],cb[L],Ci);
      if(m1==8)  k_inv_ytx8<8> <<<4*Co*16,512,0,stream>>>(Fm2,h,Co,(L!=3)?1:0);
      else       k_inv_ytx8<12><<<4*Co*16,512,0,stream>>>(Fm2,h,Co,(L!=3)?1:0);
    } else {
      // scratch lives in d_out (rewritten entirely by head at the end)
      float* Fty=out;                 // <= 1,572,864 floats
      float* Fm =out+1572864;         // <=   294,912 floats
      float* Fm2=out+1867776;         // <= 1,179,648 floats (per-b strided)
      for(int b=0;b<4;b++){
        float* hbp=h+(long)b*32*SP3;
        if(m1==8)  k_fwd_ty8<8> <<<Ci*16,512,0,stream>>>(hbp,Fty,Ci);
        else       k_fwd_ty8<12><<<Ci*16,512,0,stream>>>(hbp,Fty,Ci);
        if(m1==8)  k_fwd_x2<8,8>  <<<Ci*2,256,0,stream>>>(Fty,Fm,Ci);
        else       k_fwd_x2<12,12><<<Ci*2,256,0,stream>>>(Fty,Fm,Ci);
        k_mix<<<4*nch,Co*8,0,stream>>>(Fm,sw[L],Fm2+b*FM_B,Ci,Co,m1,m2);
      }
      if(Co==24) k_pconv2<24><<<2560,256,0,stream>>>(h,cw[L],cb[L],Ci);
      else       k_pconv2<32><<<2560,256,0,stream>>>(h,cw[L],cb[L],Ci);
      for(int b=0;b<4;b++){
        float* hbp=h+(long)b*32*SP3;
        if(m1==8)  k_inv_ytx8<8> <<<Co*16,512,0,stream>>>(Fm2+b*FM_B,hbp,Co,(L!=3)?1:0);
        else       k_inv_ytx8<12><<<Co*16,512,0,stream>>>(Fm2+b*FM_B,hbp,Co,(L!=3)?1:0);
      }
    }
  }
  if(full){
    float* w1t=ws+H_FLOATS+FTY_FULL;    // Fm region, dead by now
    k_prep_w1t<<<16,256,0,stream>>>(fc1w,w1t);
    k_head_s<<<2560,256,0,stream>>>(h,w1t,fc1b,fc2w,fc2b,out);
  } else {
    k_head2<<<2560,256,0,stream>>>(h,fc1w,fc1b,fc2w,fc2b,out);
  }
}

// Round 9
// 1810.968 us; speedup vs baseline: 1.2180x; 1.0171x over previous
//
#include <hip/hip_runtime.h>

#define TWO_PI 6.2831853071795864769f
#define SP3 327680      // 128*128*20
#define YT 2560         // 128*20

// Branch-free gelu via A&S 7.1.26 erf approximation (|eps|<=1.5e-7).
static __device__ __forceinline__ float gelu_f(float u){
  float x=u*0.7071067811865475f;
  float a=fabsf(x);
  float t=__builtin_amdgcn_rcpf(fmaf(0.3275911f,a,1.0f));
  float p=fmaf(fmaf(fmaf(fmaf(1.061405429f,t,-1.453152027f),t,1.421413741f),t,
               -0.284496736f),t,0.254829592f)*t;
  float e=__expf(-a*a);
  float er=copysignf(1.0f-p*e,x);
  return 0.5f*u*(1.0f+er);
}

// ---------------- fc0: x(B,X,Y,T,5) @ (5,20) + b -> h(B,32stride,X,Y,T), 20 ch ----
__global__ void k_fc0(const float* __restrict__ x, const float* __restrict__ w,
                      const float* __restrict__ bias, float* __restrict__ h){
  __shared__ float wl[100], bl[20];
  int tid=threadIdx.x;
  if(tid<100) wl[tid]=w[tid];
  if(tid<20) bl[tid]=bias[tid];
  __syncthreads();
  int p=blockIdx.x*256+tid;          // 0..1310719
  int b=p/SP3, sp=p-b*SP3;
  const float* xp=x+(long)p*5;
  float xi[5];
  #pragma unroll
  for(int i=0;i<5;i++) xi[i]=xp[i];
  float* hb=h+(long)(b*32)*SP3+sp;
  #pragma unroll
  for(int c=0;c<20;c++){
    float a=bl[c];
    #pragma unroll
    for(int i=0;i<5;i++) a+=xi[i]*wl[i*20+c];
    hb[(long)c*SP3]=a;
  }
}

// ------------- forward T+Y DFT over 8-x slabs. Direct global float4 row reads.
// Y-DFT uses conjugate-pair slots: one Gc read + one tw read feed slots s and 2*M2-s.
// block: 512 threads; grid: nb*Ci*16. out: Fty[(b*32+c)*128+x][slot2*8+kz] float2.
template<int M2>
__global__ __launch_bounds__(512,3) void k_fwd_ty8(const float* __restrict__ h,
                                                   float* __restrict__ Fty, int Ci){
  constexpr int J=2*M2*8;
  __shared__ float2 Gc[128*33];         // 33792 B, [y][col=xl*8+kz], pad 33
  __shared__ __align__(16) float2 tw20[160];
  __shared__ float2 tw128[128];
  int tid=threadIdx.x;
  int bid=blockIdx.x;
  int xg=bid&15, bc=bid>>4; int c=bc%Ci, b=bc/Ci;
  int x0=xg*8;
  for(int i=tid;i<160;i+=512){ int t=i>>3,kz=i&7; float s,cc;
    sincosf(TWO_PI*((kz*t)%20)/20.0f,&s,&cc); tw20[i]=make_float2(cc,s); }
  if(tid<128){ float s,cc; sincosf(TWO_PI*tid/128.0f,&s,&cc); tw128[tid]=make_float2(cc,s); }
  __syncthreads();
  const float* hb=h+(long)(b*32+c)*SP3+x0*YT;
  float2* outp=(float2*)Fty+((long)(b*32+c)*128+x0)*J;
  const float4* twp=(const float4*)tw20;   // [t*4+q] -> (c,s) for kz=2q,2q+1

  for(int half=0;half<2;half++){
    if(half) __syncthreads();             // protect Gc from prev half readers
    // ---- T-DFT: one row per thread, direct global float4 reads
    {
      int y=tid&127, xl=tid>>7;
      const float* rp=hb+(half*4+xl)*YT+y*20;
      float4 r0=*(const float4*)(rp);
      float4 r1=*(const float4*)(rp+4);
      float4 r2=*(const float4*)(rp+8);
      float4 r3=*(const float4*)(rp+12);
      float4 r4=*(const float4*)(rp+16);
      float row[20]={r0.x,r0.y,r0.z,r0.w, r1.x,r1.y,r1.z,r1.w, r2.x,r2.y,r2.z,r2.w,
                     r3.x,r3.y,r3.z,r3.w, r4.x,r4.y,r4.z,r4.w};
      float re[8],im[8];
      #pragma unroll
      for(int kz=0;kz<8;kz++){re[kz]=0.f;im[kz]=0.f;}
      #pragma unroll
      for(int t=0;t<20;t++){
        float v=row[t];
        #pragma unroll
        for(int q=0;q<4;q++){
          float4 w=twp[t*4+q];
          re[2*q]  +=v*w.x; im[2*q]  -=v*w.y;
          re[2*q+1]+=v*w.z; im[2*q+1]-=v*w.w;
        }
      }
      #pragma unroll
      for(int kz=0;kz<8;kz++) Gc[y*33+xl*8+kz]=make_float2(re[kz],im[kz]);
    }
    __syncthreads();
    // ---- Y-DFT, conjugate-paired: item=(sp,col), sp in [0,M2]
    for(int ip=tid;ip<(M2+1)*32;ip+=512){
      int col=ip&31, sp=ip>>5;
      float a1r=0.f,a1i=0.f,a2r=0.f,a2i=0.f;
      int jj=0;
      for(int y=0;y<128;y++){
        float2 w=tw128[jj];
        float2 d=Gc[y*33+col];
        float tr=d.x*w.x, ts=d.y*w.y, ur=d.y*w.x, us=d.x*w.y;
        a1r+=tr+ts; a1i+=ur-us;          // slot sp      (km=+sp)
        a2r+=tr-ts; a2i+=ur+us;          // slot 2M2-sp  (km=-sp)
        jj=(jj+sp)&127;
      }
      int xl=col>>3, kz=col&7;
      long rowoff=(long)(half*4+xl)*J;
      if(sp<M2) outp[rowoff+sp*8+kz]=make_float2(a1r,a1i);
      if(sp>=1) outp[rowoff+(2*M2-sp)*8+kz]=make_float2(a2r,a2i);
    }
  }
}

// ------------- forward X DFT, slot-split: Fty[(b*32+c)*128+x, J] -> Fm[(b*32+c), s, J]
// grid: nb*Ci*2 (sh=bid&1 -> slots [sh*M1, sh*M1+M1)), block 256.
template<int M1,int M2>
__global__ __launch_bounds__(256,3) void k_fwd_x2(const float* __restrict__ Fty,
                                                  float* __restrict__ Fm, int Ci){
  constexpr int J=2*M2*8;
  constexpr int NIT=(M1*J+255)/256;
  __shared__ float2 tile[32*J];         // <=49152 B
  __shared__ float2 tw128[128];
  int tid=threadIdx.x, bid=blockIdx.x;
  int sh=bid&1; int c=(bid>>1)%Ci; int b=bid/(2*Ci);
  if(tid<128){ float s,cc; sincosf(TWO_PI*tid/128.0f,&s,&cc); tw128[tid]=make_float2(cc,s); }
  float accr[NIT],acci[NIT];
  #pragma unroll
  for(int it=0;it<NIT;it++){accr[it]=0.f;acci[it]=0.f;}
  const float2* base=(const float2*)Fty+((long)(b*32+c)*128)*J;
  for(int xt=0;xt<4;xt++){
    __syncthreads();
    const float2* src=base+(long)xt*32*J;
    for(int idx=tid;idx<32*J;idx+=256) tile[idx]=src[idx];
    __syncthreads();
    #pragma unroll
    for(int it=0;it<NIT;it++){
      int idx=it*256+tid;
      if(idx<M1*J){
        int si=idx/J, j=idx-si*J;
        int km=(sh==0)? si : (si-M1);
        int jj=(km*(xt*32))&127;
        float ar=accr[it], ai=acci[it];
        for(int xl=0;xl<32;xl++){
          float2 w=tw128[jj];
          float2 d=tile[xl*J+j];
          ar+=d.x*w.x+d.y*w.y;
          ai+=d.y*w.x-d.x*w.y;
          jj=(jj+km)&127;
        }
        accr[it]=ar; acci[it]=ai;
      }
    }
  }
  float2* o=(float2*)Fm+(long)(b*32+c)*(2*M1)*J;
  #pragma unroll
  for(int it=0;it<NIT;it++){
    int idx=it*256+tid;
    if(idx<M1*J){
      int si=idx/J, j=idx-si*J;
      int s=sh*M1+si;
      o[(long)s*J+j]=make_float2(accr[it],acci[it]);
    }
  }
}

// ------------- mode mixing (unchanged)
__global__ void k_mix(const float* __restrict__ Fm, const float* __restrict__ w,
                      float* __restrict__ Fm2, int Ci, int Co, int m1, int m2){
  int MC=m1*m2*8;
  int nch=MC/8;
  int bid=blockIdx.x;
  int chunk=bid%nch; int q=(bid/nch)&3; int b=bid/(4*nch);
  int tid=threadIdx.x;
  int M1S=2*m1, M2S=2*m2;
  int J=M2S*8;
  __shared__ float fin[32*16];
  for(int idx=tid;idx<Ci*16;idx+=blockDim.x){
    int i=idx>>4; int r=idx&15; int mll=r>>1; int ri=r&1;
    int mg=chunk*8+mll;
    int mx=mg/(m2*8); int my=(mg>>3)%m2; int kz=mg&7;
    int sx=(q&1)?(m1+mx):mx; int sy=(q&2)?(m2+my):my;
    fin[idx]=Fm[((long)((b*32+i)*M1S+sx)*J+sy*8+kz)*2+ri];
  }
  __syncthreads();
  int ml=tid&7, o=tid>>3;
  int mg=chunk*8+ml;
  int mx=mg/(m2*8); int my=(mg>>3)%m2; int kz=mg&7;
  int sx=(q&1)?(m1+mx):mx; int sy=(q&2)?(m2+my):my;
  int moff=(mx*m2+my)*8+kz;
  const float* wr=w+(long)(q*2)*Ci*Co*MC+o*MC+moff;
  const float* wi=wr+(long)Ci*Co*MC;
  long wstep=(long)Co*MC;
  float re=0.f, im=0.f;
  for(int i=0;i<Ci;i++){
    float ar=fin[i*16+ml*2], ai=fin[i*16+ml*2+1];
    float wrv=wr[i*wstep], wiv=wi[i*wstep];
    re+=ar*wrv-ai*wiv;
    im+=ar*wiv+ai*wrv;
  }
  long oidx=((long)((b*32+o)*M1S+sx)*J+sy*8+kz)*2;
  Fm2[oidx]=re; Fm2[oidx+1]=im;
}

// ------------- FUSED inverse X + inverse Y + inverse T + coalesced float4 RMW + gelu.
// block: 512 threads; grid: nb*Co*16. Fm2: [(b*32+oc)][s1][J] float2.
// All non-broadcast LDS accesses are float2 (2-way alias = free); tw20p stride-9 pad.
template<int M>
__global__ __launch_bounds__(512,3) void k_inv_ytx8(const float* __restrict__ Fm2,
                                                    float* h, int Co, int do_gelu){
  constexpr int S1=2*M, S2=2*M;
  constexpr int J=S2*8;
  constexpr int UN=( (S1*J) > (128*33) ? (S1*J) : (128*33) );
  __shared__ __align__(16) float2 uni[UN];     // Fm2s, later Gc
  __shared__ __align__(16) float2 g1s[S2*66];  // [s2][xl*8+kz], row stride 66
  __shared__ float2 tw20p[20*9];               // padded [t*9+kz]
  __shared__ float2 tw128[128];
  int tid=threadIdx.x;
  int bid=blockIdx.x;
  int xg=bid&15, bo=bid>>4; int oc=bo%Co, b=bo/Co;
  int x0=xg*8;
  for(int i=tid;i<160;i+=512){ int t=i>>3,kz=i&7; float s,cc;
    sincosf(TWO_PI*((kz*t)%20)/20.0f,&s,&cc); tw20p[t*9+kz]=make_float2(cc,s); }
  if(tid<128){ float s,cc; sincosf(TWO_PI*tid/128.0f,&s,&cc); tw128[tid]=make_float2(cc,s); }
  // ---- stage Fm2 tile (coalesced)
  float2* Fm2s=uni;
  const float2* src=(const float2*)Fm2+(long)(b*32+oc)*S1*J;
  for(int idx=tid;idx<S1*J;idx+=512) Fm2s[idx]=src[idx];
  __syncthreads();
  // ---- inverse X: float2 reads (lane word-stride 2 -> conflict-free).
  for(int idx=tid;idx<8*J;idx+=512){
    int xl=idx/J, j=idx-xl*J;
    int xgl=x0+xl;
    float re=0.f, im=0.f;
    int jj=0;
    for(int s=0;s<M;s++){
      float2 w=tw128[jj]; float2 d=Fm2s[s*J+j];
      re+=d.x*w.x-d.y*w.y;
      im+=d.x*w.y+d.y*w.x;
      jj=(jj+xgl)&127;
    }
    jj=((128-M)*xgl)&127;
    for(int s=M;s<S1;s++){
      float2 w=tw128[jj]; float2 d=Fm2s[s*J+j];
      re+=d.x*w.x-d.y*w.y;
      im+=d.x*w.y+d.y*w.x;
      jj=(jj+xgl)&127;
    }
    g1s[(j>>3)*66 + xl*8 + (j&7)]=make_float2(re,im);
  }
  __syncthreads();                      // Fm2s dead; uni becomes Gc
  float2* Gc=uni;                       // [y][xlh*8+kz], stride 33
  const float invN=1.0f/(128.0f*128.0f*20.0f);
  float* hb=h+(long)(b*32+oc)*SP3+x0*YT;
  const float4* g4c=(const float4*)g1s;
  for(int half=0;half<2;half++){
    // ---- phase A: inverse-Y into registers; lanes=y, xlh wave-uniform.
    int y=tid&127, xlh=tid>>7;
    int xlg=half*4+xlh;
    float gyr[8],gyi[8];
    #pragma unroll
    for(int kz=0;kz<8;kz++){gyr[kz]=0.f;gyi[kz]=0.f;}
    for(int s=0;s<S2;s++){
      int km=(s<M)?s:(s-S2);
      float2 w=tw128[(km*y)&127];
      int base=(s*66+xlg*8)>>1;
      #pragma unroll
      for(int q=0;q<4;q++){
        float4 d=g4c[base+q];           // wave-uniform broadcast b128
        gyr[2*q]  +=d.x*w.x-d.y*w.y;  gyi[2*q]  +=d.x*w.y+d.y*w.x;
        gyr[2*q+1]+=d.z*w.x-d.w*w.y;  gyi[2*q+1]+=d.z*w.y+d.w*w.x;
      }
    }
    #pragma unroll
    for(int kz=0;kz<8;kz++) Gc[y*33+xlh*8+kz]=make_float2(gyr[kz],gyi[kz]);
    __syncthreads();
    // ---- phase B: inverse-T per float4 task, direct coalesced global RMW.
    for(int task=tid;task<2560;task+=512){
      int r=task/5, q=task-r*5;         // r=(xlh2,y), q = which float4 of the row
      int xlh2=r>>7, yy=r&127;
      float gr[8],gi[8];
      #pragma unroll
      for(int kz=0;kz<8;kz++){ float2 d=Gc[yy*33+xlh2*8+kz]; gr[kz]=d.x; gi[kz]=d.y; }
      float o[4];
      #pragma unroll
      for(int u=0;u<4;u++){
        int t=4*q+u;
        float v=gr[0];
        #pragma unroll
        for(int kz=1;kz<8;kz++){
          float2 w=tw20p[t*9+kz];
          v+=2.0f*(gr[kz]*w.x-gi[kz]*w.y);
        }
        o[u]=v*invN;
      }
      float* dp=hb+(long)(half*4+xlh2)*YT+yy*20+4*q;
      float4 hv=*(const float4*)dp;
      float4 ov;
      ov.x=hv.x+o[0]; ov.y=hv.y+o[1]; ov.z=hv.z+o[2]; ov.w=hv.w+o[3];
      if(do_gelu){ov.x=gelu_f(ov.x);ov.y=gelu_f(ov.y);ov.z=gelu_f(ov.z);ov.w=gelu_f(ov.w);}
      *(float4*)dp=ov;
    }
    __syncthreads();                    // Gc reused next half
  }
}

// ------------- pointwise conv IN-PLACE, float2 point-pairs, float4 weight broadcasts.
template<int CO>
__global__ __launch_bounds__(256,4) void k_pconv2(float* h, const float* __restrict__ w,
                                                  const float* __restrict__ bias, int Ci){
  __shared__ __align__(16) float wt[32*CO];   // [i][o]
  __shared__ float bl[CO];
  int tid=threadIdx.x;
  for(int idx=tid;idx<Ci*CO;idx+=256){int i=idx/CO,o=idx-i*CO; wt[idx]=w[o*Ci+i];}
  if(tid<CO) bl[tid]=bias[tid];
  __syncthreads();
  long p=(long)blockIdx.x*512+tid*2;   // points p, p+1 (contiguous pair)
  int b=(int)(p/SP3); int sp=(int)(p-(long)b*SP3);
  float* hb=h+(long)b*32*SP3+sp;
  float acc0[CO],acc1[CO];
  #pragma unroll
  for(int o=0;o<CO;o++){acc0[o]=bl[o];acc1[o]=bl[o];}
  for(int i=0;i<Ci;i++){
    float2 v=*(const float2*)&hb[(long)i*SP3];
    const float4* wc=(const float4*)&wt[i*CO];
    #pragma unroll
    for(int o4=0;o4<CO/4;o4++){
      float4 ww=wc[o4];
      acc0[4*o4+0]+=v.x*ww.x; acc0[4*o4+1]+=v.x*ww.y;
      acc0[4*o4+2]+=v.x*ww.z; acc0[4*o4+3]+=v.x*ww.w;
      acc1[4*o4+0]+=v.y*ww.x; acc1[4*o4+1]+=v.y*ww.y;
      acc1[4*o4+2]+=v.y*ww.z; acc1[4*o4+3]+=v.y*ww.w;
    }
  }
  #pragma unroll
  for(int o=0;o<CO;o++){
    *(float2*)&hb[(long)o*SP3]=make_float2(acc0[o],acc1[o]);
  }
}

// ------------- prep: transpose w1 (32x128 [i][jj]) -> w1t (128x32 [jj][i])
__global__ void k_prep_w1t(const float* __restrict__ w1, float* __restrict__ w1t){
  int idx=blockIdx.x*256+threadIdx.x;
  if(idx<4096){ int jj=idx>>5, i=idx&31; w1t[idx]=w1[i*128+jj]; }
}

// ------------- head, scalar-operand weights: fc1(32->128)+gelu, fc2(128->3).
__global__ __launch_bounds__(256,3) void k_head_s(const float* __restrict__ h,
                       const float* __restrict__ w1t, const float* __restrict__ b1,
                       const float* __restrict__ w2, const float* __restrict__ b2,
                       float* __restrict__ out){
  long p=(long)blockIdx.x*512+threadIdx.x;
  int b=(int)(p/SP3); int sp=(int)(p-(long)b*SP3);
  const float* hb=h+(long)b*32*SP3+sp;
  float hv0[32],hv1[32];
  #pragma unroll
  for(int i=0;i<32;i++){hv0[i]=hb[(long)i*SP3]; hv1[i]=hb[(long)i*SP3+256];}
  float a00=b2[0],a01=b2[1],a02=b2[2];
  float a10=a00,a11=a01,a12=a02;
  for(int jj=0;jj<128;jj++){
    const float* wc=w1t+jj*32;
    float u0=b1[jj], u1=u0;
    #pragma unroll
    for(int q=0;q<32;q++){
      float ww=wc[q];
      u0+=hv0[q]*ww;
      u1+=hv1[q]*ww;
    }
    u0=gelu_f(u0); u1=gelu_f(u1);
    float w20=w2[jj*3], w21=w2[jj*3+1], w22=w2[jj*3+2];
    a00+=u0*w20; a01+=u0*w21; a02+=u0*w22;
    a10+=u1*w20; a11+=u1*w21; a12+=u1*w22;
  }
  float* op=out+p*3;
  op[0]=a00; op[1]=a01; op[2]=a02;
  op=out+(p+256)*3;
  op[0]=a10; op[1]=a11; op[2]=a12;
}

// ------------- head fallback (LDS weights) for the low-workspace path
__global__ __launch_bounds__(256,4) void k_head2(const float* __restrict__ h,
                       const float* __restrict__ w1, const float* __restrict__ b1,
                       const float* __restrict__ w2, const float* __restrict__ b2,
                       float* __restrict__ out){
  __shared__ __align__(16) float w1t[128*32];   // [jj][i]
  __shared__ float b1l[128];
  __shared__ __align__(16) float4 w2l[128];
  __shared__ float b2l[3];
  int tid=threadIdx.x;
  for(int idx=tid;idx<4096;idx+=256){int jj=idx>>5,i=idx&31; w1t[idx]=w1[i*128+jj];}
  if(tid<128){b1l[tid]=b1[tid]; w2l[tid]=make_float4(w2[tid*3],w2[tid*3+1],w2[tid*3+2],0.f);}
  if(tid<3) b2l[tid]=b2[tid];
  __syncthreads();
  long p=(long)blockIdx.x*512+tid;
  int b=(int)(p/SP3); int sp=(int)(p-(long)b*SP3);
  const float* hb=h+(long)b*32*SP3+sp;
  float hv0[32],hv1[32];
  #pragma unroll
  for(int i=0;i<32;i++){hv0[i]=hb[(long)i*SP3]; hv1[i]=hb[(long)i*SP3+256];}
  float a00=b2l[0],a01=b2l[1],a02=b2l[2];
  float a10=a00,a11=a01,a12=a02;
  for(int jj=0;jj<128;jj++){
    const float4* wc=(const float4*)&w1t[jj*32];
    float u0=b1l[jj], u1=u0;
    #pragma unroll
    for(int q=0;q<8;q++){
      float4 ww=wc[q];
      u0+=hv0[4*q]*ww.x+hv0[4*q+1]*ww.y+hv0[4*q+2]*ww.z+hv0[4*q+3]*ww.w;
      u1+=hv1[4*q]*ww.x+hv1[4*q+1]*ww.y+hv1[4*q+2]*ww.z+hv1[4*q+3]*ww.w;
    }
    u0=gelu_f(u0); u1=gelu_f(u1);
    float4 w2v=w2l[jj];
    a00+=u0*w2v.x; a01+=u0*w2v.y; a02+=u0*w2v.z;
    a10+=u1*w2v.x; a11+=u1*w2v.y; a12+=u1*w2v.z;
  }
  float* op=out+p*3;
  op[0]=a00; op[1]=a01; op[2]=a02;
  op=out+(p+256)*3;
  op[0]=a10; op[1]=a11; op[2]=a12;
}

extern "C" void kernel_launch(void* const* d_in, const int* in_sizes, int n_in,
                              void* d_out, int out_size, void* d_ws, size_t ws_size,
                              hipStream_t stream){
  (void)in_sizes; (void)n_in; (void)out_size;
  const float* x    =(const float*)d_in[0];
  const float* fc0w =(const float*)d_in[1];
  const float* fc0b =(const float*)d_in[2];
  const float* sw[4]={(const float*)d_in[3],(const float*)d_in[6],(const float*)d_in[9],(const float*)d_in[12]};
  const float* cw[4]={(const float*)d_in[4],(const float*)d_in[7],(const float*)d_in[10],(const float*)d_in[13]};
  const float* cb[4]={(const float*)d_in[5],(const float*)d_in[8],(const float*)d_in[11],(const float*)d_in[14]};
  const float* fc1w =(const float*)d_in[15];
  const float* fc1b =(const float*)d_in[16];
  const float* fc2w =(const float*)d_in[17];
  const float* fc2b =(const float*)d_in[18];
  float* out=(float*)d_out;
  float* ws=(float*)d_ws;

  const long H_FLOATS   = 41943040L;            // 4*32*327680 (168 MB)
  const long FTY_FULL   = 6291456L;             // 4*32*128*192*2
  const long FM_FULL    = 1179648L;             // 4*32*24*192*2
  const long NEED_FULL  = H_FLOATS + FTY_FULL + 2*FM_FULL;

  float* h = ws;
  bool full = (ws_size >= (size_t)NEED_FULL*4);

  const int LAY[5]={20,24,24,32,32};
  const int M1A[4]={8,8,12,12};

  k_fc0<<<5120,256,0,stream>>>(x,fc0w,fc0b,h);

  for(int L=0;L<4;L++){
    int Ci=LAY[L], Co=LAY[L+1], m1=M1A[L], m2=M1A[L];
    int nch=m1*m2;
    long FM_B=(long)32*(2*m1)*(2*m2*8)*2;

    if(full){
      float* Fty=ws+H_FLOATS;
      float* Fm =ws+H_FLOATS+FTY_FULL;
      float* Fm2=ws+H_FLOATS+FTY_FULL+FM_FULL;
      if(m1==8)  k_fwd_ty8<8> <<<4*Ci*16,512,0,stream>>>(h,Fty,Ci);
      else       k_fwd_ty8<12><<<4*Ci*16,512,0,stream>>>(h,Fty,Ci);
      if(m1==8)  k_fwd_x2<8,8>  <<<4*Ci*2,256,0,stream>>>(Fty,Fm,Ci);
      else       k_fwd_x2<12,12><<<4*Ci*2,256,0,stream>>>(Fty,Fm,Ci);
      k_mix<<<4*4*nch,Co*8,0,stream>>>(Fm,sw[L],Fm2,Ci,Co,m1,m2);
      if(Co==24) k_pconv2<24><<<2560,256,0,stream>>>(h,cw[L],cb[L],Ci);
      else       k_pconv2<32><<<2560,256,0,stream>>>(h,cw[L],cb[L],Ci);
      if(m1==8)  k_inv_ytx8<8> <<<4*Co*16,512,0,stream>>>(Fm2,h,Co,(L!=3)?1:0);
      else       k_inv_ytx8<12><<<4*Co*16,512,0,stream>>>(Fm2,h,Co,(L!=3)?1:0);
    } else {
      // scratch lives in d_out (rewritten entirely by head at the end)
      float* Fty=out;                 // <= 1,572,864 floats
      float* Fm =out+1572864;         // <=   294,912 floats
      float* Fm2=out+1867776;         // <= 1,179,648 floats (per-b strided)
      for(int b=0;b<4;b++){
        float* hbp=h+(long)b*32*SP3;
        if(m1==8)  k_fwd_ty8<8> <<<Ci*16,512,0,stream>>>(hbp,Fty,Ci);
        else       k_fwd_ty8<12><<<Ci*16,512,0,stream>>>(hbp,Fty,Ci);
        if(m1==8)  k_fwd_x2<8,8>  <<<Ci*2,256,0,stream>>>(Fty,Fm,Ci);
        else       k_fwd_x2<12,12><<<Ci*2,256,0,stream>>>(Fty,Fm,Ci);
        k_mix<<<4*nch,Co*8,0,stream>>>(Fm,sw[L],Fm2+b*FM_B,Ci,Co,m1,m2);
      }
      if(Co==24) k_pconv2<24><<<2560,256,0,stream>>>(h,cw[L],cb[L],Ci);
      else       k_pconv2<32><<<2560,256,0,stream>>>(h,cw[L],cb[L],Ci);
      for(int b=0;b<4;b++){
        float* hbp=h+(long)b*32*SP3;
        if(m1==8)  k_inv_ytx8<8> <<<Co*16,512,0,stream>>>(Fm2+b*FM_B,hbp,Co,(L!=3)?1:0);
        else       k_inv_ytx8<12><<<Co*16,512,0,stream>>>(Fm2+b*FM_B,hbp,Co,(L!=3)?1:0);
      }
    }
  }
  if(full){
    float* w1t=ws+H_FLOATS+FTY_FULL;    // Fm region, dead by now
    k_prep_w1t<<<16,256,0,stream>>>(fc1w,w1t);
    k_head_s<<<2560,256,0,stream>>>(h,w1t,fc1b,fc2w,fc2b,out);
  } else {
    k_head2<<<2560,256,0,stream>>>(h,fc1w,fc1b,fc2w,fc2b,out);
  }
}